// Round 4
// baseline (3073.249 us; speedup 1.0000x reference)
//
#include <hip/hip_runtime.h>
#include <math.h>

#define T_TASKS 64
#define NS 75
#define NW 5
#define NTOT 375
#define NQ 150
#define DIM 4096
#define QP_ITERS 15
#define SIGMA 0.1f
#define CREG 0.1f

// workspace layout (float offsets), within the proven 10.1 MB footprint.
// OFF_W region (2,048,000 fl) holds gram triangle partials (8*64*2850 =
// 1,459,200 fl) before the QP solve, then vbuf (1,310,720 fl) after it.
#define OFF_K   0u
#define OFF_W   369664u
#define OFF_Z   2417664u
#define TRI_SZ  2850   // 75*76/2 lower-triangle floats per (chunk, task)

// ------------------------------------------- gram partials, 8 chunks of 512 d.
// 512 blocks (2/CU). Per block: 8 sub-chunks of 64 d, double-buffered LDS,
// global loads issued one sub-chunk ahead (latency hidden under compute).
// Output: lower triangle only (K symmetric), plain stores, no atomics.
__global__ __launch_bounds__(256) void gram8(const float* __restrict__ support,
                                             float* __restrict__ Kp) {
    int p = blockIdx.x, b = blockIdx.y;
    __shared__ __align__(16) float Ss[2][80][68];
    int tid = threadIdx.x;
    int tx = tid & 15, ty = tid >> 4;
    float acc[5][5];
#pragma unroll
    for (int u = 0; u < 5; u++)
#pragma unroll
        for (int v = 0; v < 5; v++) acc[u][v] = 0.f;
    const float* sb = support + (size_t)b * NS * DIM + p * 512;

    float4 pf[5];
    // issue loads for sub-chunk c into pf
#define G8_ISSUE(c)                                                        \
    {                                                                      \
        _Pragma("unroll")                                                  \
        for (int j = 0; j < 5; j++) {                                      \
            int idx = tid + 256 * j;                                       \
            int r = idx >> 4, q = idx & 15;                                \
            pf[j] = (r < 75) ? *(const float4*)&sb[(size_t)r * DIM + (c) * 64 + q * 4] \
                             : make_float4(0.f, 0.f, 0.f, 0.f);            \
        }                                                                  \
    }
#define G8_COMMIT(c)                                                       \
    {                                                                      \
        _Pragma("unroll")                                                  \
        for (int j = 0; j < 5; j++) {                                      \
            int idx = tid + 256 * j;                                       \
            int r = idx >> 4, q = idx & 15;                                \
            *(float4*)&Ss[(c) & 1][r][q * 4] = pf[j];                      \
        }                                                                  \
    }
    G8_ISSUE(0);
    G8_COMMIT(0);
    for (int c = 0; c < 8; c++) {
        if (c < 7) G8_ISSUE(c + 1);
        __syncthreads();
        for (int d4 = 0; d4 < 16; d4++) {
            float4 av[5], bv[5];
#pragma unroll
            for (int u = 0; u < 5; u++) av[u] = *(const float4*)&Ss[c & 1][ty * 5 + u][d4 * 4];
#pragma unroll
            for (int v = 0; v < 5; v++) bv[v] = *(const float4*)&Ss[c & 1][tx * 5 + v][d4 * 4];
#pragma unroll
            for (int u = 0; u < 5; u++)
#pragma unroll
                for (int v = 0; v < 5; v++)
                    acc[u][v] += av[u].x * bv[v].x + av[u].y * bv[v].y +
                                 av[u].z * bv[v].z + av[u].w * bv[v].w;
        }
        if (c < 7) G8_COMMIT(c + 1);
    }
    float* Ko = Kp + (size_t)(p * 64 + b) * TRI_SZ;
#pragma unroll
    for (int u = 0; u < 5; u++) {
        int row = ty * 5 + u;
#pragma unroll
        for (int v = 0; v < 5; v++) {
            int col = tx * 5 + v;
            if (row < 75 && col < 75 && row >= col)
                Ko[row * (row + 1) / 2 + col] = acc[u][v];
        }
    }
}

// reduce 8 triangle partials into padded symmetric Kg (pad diag = 1)
__global__ void gram_reduce(const float* __restrict__ Kp, float* __restrict__ Kg) {
    int idx = blockIdx.x * 256 + threadIdx.x;
    if (idx >= T_TASKS * 5776) return;
    int b = idx / 5776, rc = idx % 5776;
    int row = rc / 76, col = rc % 76;
    float val;
    if (row < 75 && col < 75) {
        int i = row > col ? row : col, j = row > col ? col : row;
        int t = i * (i + 1) / 2 + j;
        val = 0.f;
#pragma unroll
        for (int p = 0; p < 8; p++)
            val += Kp[(size_t)(p * 64 + b) * TRI_SZ + t];
    } else {
        val = (row == col) ? 1.f : 0.f;
    }
    Kg[idx] = val;
}

// --------------- register-resident Gauss-Jordan of NM 80x80 matrices at once
// (pad rows/cols >=75 are identity). Thread (ty,tx) owns rows {ty+16m} x cols
// {tx+16n}. One barrier per pivot step serves all NM chains (latency of the
// LDS broadcasts hides under the other chains' FMA updates).
// Update uses the column-pre-fix formulation: set M[:,k] := e_k, then
// pv2[c] = (c==k)?1:prow[c]; fv2[r] = (r==k)?(1-pinv):fcol[r]*pinv;
// M -= fv2*pv2 — a pure rank-1 FMA, no per-element selects.
template <int NM>
__device__ __forceinline__ void reg_gj_multi(float (&M)[NM][5][5],
                                             float (*prow)[2][80],
                                             float (*fcol)[2][80],
                                             int tx, int ty) {
    for (int k = 0; k < 75; k++) {
        int bf = k & 1;
        int km = k & 15, kd = k >> 4;
        if (ty == km) {
#pragma unroll
            for (int m = 0; m < 5; m++)
                if (ty + 16 * m == k) {
#pragma unroll
                    for (int w = 0; w < NM; w++)
#pragma unroll
                        for (int n = 0; n < 5; n++)
                            prow[w][bf][tx + 16 * n] = M[w][m][n];
                }
        }
        if (tx == km) {
#pragma unroll
            for (int n = 0; n < 5; n++)
                if (tx + 16 * n == k) {
#pragma unroll
                    for (int w = 0; w < NM; w++)
#pragma unroll
                        for (int m = 0; m < 5; m++)
                            fcol[w][bf][ty + 16 * m] = M[w][m][n];
                }
        }
        __syncthreads();
        // column-k pre-fix: M[:,k] := e_k (kd is wave-uniform -> scalar branch)
        if (tx == km) {
#pragma unroll
            for (int n = 0; n < 5; n++)
                if (n == kd) {
#pragma unroll
                    for (int w = 0; w < NM; w++)
#pragma unroll
                        for (int m = 0; m < 5; m++)
                            M[w][m][n] = (ty + 16 * m == k) ? 1.f : 0.f;
                }
        }
#pragma unroll
        for (int w = 0; w < NM; w++) {
            float pinv = 1.f / prow[w][bf][k];
            float pv2[5], fv2[5];
#pragma unroll
            for (int n = 0; n < 5; n++) {
                int c = tx + 16 * n;
                float pp = prow[w][bf][c];
                pv2[n] = (c == k) ? 1.f : pp;
            }
#pragma unroll
            for (int m = 0; m < 5; m++) {
                int r = ty + 16 * m;
                float f = fcol[w][bf][r] * pinv;
                fv2[m] = (r == k) ? (1.f - pinv) : f;
            }
#pragma unroll
            for (int m = 0; m < 5; m++)
#pragma unroll
                for (int n = 0; n < 5; n++)
                    M[w][m][n] -= fv2[m] * pv2[n];
        }
    }
}

// ------------------------------------- one block per task owns the ENTIRE
// QP loop: state (z,s,lam,nu) LDS-resident, K in registers, all 5 W_w in
// registers; 15 iterations with only __syncthreads(); zero global traffic
// in the loop, zero inter-block sync. Writes z at the end.
__global__ __launch_bounds__(256, 1) void qp_solve(
        const float* __restrict__ Kg, const int* __restrict__ labels,
        float* __restrict__ zout) {
    int b = blockIdx.x;
    int tid = threadIdx.x;
    int tx = tid & 15, ty = tid >> 4;

    __shared__ float prow[5][2][80], fcol[5][2][80];
    __shared__ float zs[400], ss[400], ls[400];
    __shared__ float nus[80];
    __shared__ int labv[80];
    __shared__ float r1w[5][80], Dv[5][80], tvs[5][80], dzs[5][80];
    __shared__ float rhs[80], dnu[80], mred[4], ared[4];

    // K tile in registers (pad rows/cols >=76 identity; Kg already pads 75)
    float Kreg[5][5];
    const float* Kt = Kg + (size_t)b * 5776;
#pragma unroll
    for (int m = 0; m < 5; m++) {
        int r = ty + 16 * m;
#pragma unroll
        for (int n = 0; n < 5; n++) {
            int c = tx + 16 * n;
            Kreg[m][n] = (r < 76 && c < 76) ? Kt[r * 76 + c] : ((r == c) ? 1.f : 0.f);
        }
    }
    // state init (pads zeroed)
    for (int idx = tid; idx < 400; idx += 256) {
        zs[idx] = 0.f;
        ss[idx] = (idx < NTOT) ? 1.f : 0.f;
        ls[idx] = (idx < NTOT) ? 1.f : 0.f;
    }
    if (tid < 80) {
        nus[tid] = 0.f;
        labv[tid] = (tid < 75) ? labels[b * NS + tid] : -1;
    }
    __syncthreads();

    float MW[5][5][5];   // the five W_w register tiles
    float S[1][5][5];    // schur sum

    for (int it = 0; it < QP_ITERS; it++) {
        // ---- mu = mean(lam * s)
        {
            float part = 0.f;
            for (int idx = tid; idx < NTOT; idx += 256) part += ls[idx] * ss[idx];
#pragma unroll
            for (int off = 32; off > 0; off >>= 1) part += __shfl_xor(part, off, 64);
            if ((tid & 63) == 0) mred[tid >> 6] = part;
        }
        __syncthreads();
        float mu = (mred[0] + mred[1] + mred[2] + mred[3]) * (1.f / (float)NTOT);

        // ---- per-w residuals: gz = K z_w, then r1_w, D_w
#pragma unroll
        for (int w = 0; w < 5; w++) {
            float gp[5];
#pragma unroll
            for (int m = 0; m < 5; m++) {
                float a = 0.f;
#pragma unroll
                for (int n = 0; n < 5; n++) a += Kreg[m][n] * zs[(tx + 16 * n) * 5 + w];
                gp[m] = a;
            }
#pragma unroll
            for (int off = 1; off < 16; off <<= 1)
#pragma unroll
                for (int m = 0; m < 5; m++) gp[m] += __shfl_xor(gp[m], off, 64);
            if (tx == 0) {
#pragma unroll
                for (int m = 0; m < 5; m++) {
                    int r = ty + 16 * m;
                    float val = 0.f, dv = 0.f;
                    if (r < 75) {
                        float sv = ss[r * 5 + w], lv = ls[r * 5 + w], zv = zs[r * 5 + w];
                        float e = (labv[r] == w) ? -1.f : 0.f;
                        float h = (labv[r] == w) ? CREG : 0.f;
                        float rz = gp[m] + zv + e + lv + nus[r];
                        float rs = zv + sv - h;
                        val = -rz - (lv * rs - lv * sv + SIGMA * mu) / sv;
                        dv = lv / sv;
                    }
                    r1w[w][r] = val;
                    Dv[w][r] = dv;
                }
            }
        }
        __syncthreads();

        // ---- build H_w = K + I + diag(D_w) in registers
#pragma unroll
        for (int w = 0; w < 5; w++) {
            float dval[5];
#pragma unroll
            for (int m = 0; m < 5; m++) dval[m] = Dv[w][ty + 16 * m];
#pragma unroll
            for (int m = 0; m < 5; m++) {
                int r = ty + 16 * m;
#pragma unroll
                for (int n = 0; n < 5; n++) {
                    float v = Kreg[m][n];
                    if (m == n && tx == ty && r < 75) v += 1.f + dval[m];
                    MW[w][m][n] = v;
                }
            }
        }

        // ---- five interleaved GJ inversions: MW[w] = H_w^{-1}
        reg_gj_multi<5>(MW, prow, fcol, tx, ty);

        // ---- t_w = W_w r1_w
#pragma unroll
        for (int w = 0; w < 5; w++) {
            float tp[5];
#pragma unroll
            for (int m = 0; m < 5; m++) {
                float a = 0.f;
#pragma unroll
                for (int n = 0; n < 5; n++) a += MW[w][m][n] * r1w[w][tx + 16 * n];
                tp[m] = a;
            }
#pragma unroll
            for (int off = 1; off < 16; off <<= 1)
#pragma unroll
                for (int m = 0; m < 5; m++) tp[m] += __shfl_xor(tp[m], off, 64);
            if (tx == 0) {
#pragma unroll
                for (int m = 0; m < 5; m++) tvs[w][ty + 16 * m] = tp[m];
            }
        }
        __syncthreads();

        // ---- S = sum_w W_w (registers); rhs
#pragma unroll
        for (int m = 0; m < 5; m++)
#pragma unroll
            for (int n = 0; n < 5; n++) {
                float a = MW[0][m][n];
#pragma unroll
                for (int w = 1; w < 5; w++) a += MW[w][m][n];
                S[0][m][n] = a;
            }
        if (tid < 80) {
            float rv = 0.f;
            if (tid < 75) {
#pragma unroll
                for (int w = 0; w < 5; w++) rv += zs[tid * 5 + w] + tvs[w][tid];
            }
            rhs[tid] = rv;
        }
        __syncthreads();

        // ---- S^{-1}
        reg_gj_multi<1>(S, prow, fcol, tx, ty);

        // ---- dnu = S^{-1} rhs
        {
            float tp[5];
#pragma unroll
            for (int m = 0; m < 5; m++) {
                float a = 0.f;
#pragma unroll
                for (int n = 0; n < 5; n++) a += S[0][m][n] * rhs[tx + 16 * n];
                tp[m] = a;
            }
#pragma unroll
            for (int off = 1; off < 16; off <<= 1)
#pragma unroll
                for (int m = 0; m < 5; m++) tp[m] += __shfl_xor(tp[m], off, 64);
            if (tx == 0) {
#pragma unroll
                for (int m = 0; m < 5; m++) dnu[ty + 16 * m] = tp[m];
            }
        }
        __syncthreads();

        // ---- dz_w = t_w - W_w dnu
#pragma unroll
        for (int w = 0; w < 5; w++) {
            float tp[5];
#pragma unroll
            for (int m = 0; m < 5; m++) {
                float a = 0.f;
#pragma unroll
                for (int n = 0; n < 5; n++) a += MW[w][m][n] * dnu[tx + 16 * n];
                tp[m] = a;
            }
#pragma unroll
            for (int off = 1; off < 16; off <<= 1)
#pragma unroll
                for (int m = 0; m < 5; m++) tp[m] += __shfl_xor(tp[m], off, 64);
            if (tx == 0) {
#pragma unroll
                for (int m = 0; m < 5; m++) {
                    int r = ty + 16 * m;
                    dzs[w][r] = tvs[w][r] - tp[m];
                }
            }
        }
        __syncthreads();

        // ---- elementwise ds/dlam + step-length + state update
        float rat = INFINITY;
        float dzv[2], dsv[2], dlv[2], zlv[2], slv[2], llv[2];
#pragma unroll
        for (int pass = 0; pass < 2; pass++) {
            int c = tid + 256 * pass;
            dzv[pass] = 0.f; dsv[pass] = 0.f; dlv[pass] = 0.f;
            zlv[pass] = 0.f; slv[pass] = 1.f; llv[pass] = 0.f;
            if (c < NTOT) {
                int i = c / 5, w = c - (c / 5) * 5;
                float dz_t = dzs[w][i];
                float zl = zs[c], sl = ss[c], ll = ls[c];
                float h = (labv[i] == w) ? CREG : 0.f;
                float rs = zl + sl - h;
                float ds_t = -rs - dz_t;
                float dl_t = (ll * dz_t + ll * rs - ll * sl + SIGMA * mu) / sl;
                zlv[pass] = zl; slv[pass] = sl; llv[pass] = ll;
                dzv[pass] = dz_t; dsv[pass] = ds_t; dlv[pass] = dl_t;
                float rr1 = (ds_t < 0.f) ? (-sl / ds_t) : INFINITY;
                float rr2 = (dl_t < 0.f) ? (-ll / dl_t) : INFINITY;
                rat = fminf(rat, fminf(rr1, rr2));
            }
        }
#pragma unroll
        for (int off = 32; off > 0; off >>= 1) rat = fminf(rat, __shfl_xor(rat, off, 64));
        if ((tid & 63) == 0) ared[tid >> 6] = rat;
        __syncthreads();
        float alpha = fminf(1.f, 0.99f * fminf(fminf(ared[0], ared[1]), fminf(ared[2], ared[3])));
#pragma unroll
        for (int pass = 0; pass < 2; pass++) {
            int c = tid + 256 * pass;
            if (c < NTOT) {
                zs[c] = zlv[pass] + alpha * dzv[pass];
                ss[c] = slv[pass] + alpha * dsv[pass];
                ls[c] = llv[pass] + alpha * dlv[pass];
            }
        }
        if (tid < 75) nus[tid] += alpha * dnu[tid];
        __syncthreads();
    }

    for (int idx = tid; idx < NTOT; idx += 256) zout[b * NTOT + idx] = zs[idx];
}

// ------------------------------ v[b,w,:] = sum_s z[b,s,w] * support[b,s,:]
__global__ __launch_bounds__(256) void v_kernel(const float* __restrict__ support,
                                                const float* __restrict__ z,
                                                float* __restrict__ vbuf) {
    int dc = blockIdx.x, b = blockIdx.y;
    __shared__ float zsm[NTOT];
    int tid = threadIdx.x;
    for (int idx = tid; idx < NTOT; idx += 256) zsm[idx] = z[b * NTOT + idx];
    __syncthreads();
    int d = dc * 256 + tid;
    float acc[5] = {0.f, 0.f, 0.f, 0.f, 0.f};
    const float* sb = support + (size_t)b * NS * DIM + d;
    for (int ssi = 0; ssi < NS; ssi++) {
        float svv = sb[(size_t)ssi * DIM];
#pragma unroll
        for (int w = 0; w < 5; w++) acc[w] += svv * zsm[ssi * 5 + w];
    }
#pragma unroll
    for (int w = 0; w < 5; w++) vbuf[(size_t)(b * NW + w) * DIM + d] = acc[w];
}

// -------------------- logits[b,q,w] = sum_d query[b,q,d] * v[b,w,d]
__global__ __launch_bounds__(256) void logits_kernel(const float* __restrict__ query,
                                                     const float* __restrict__ vbuf,
                                                     float* __restrict__ out) {
    int qt = blockIdx.x, b = blockIdx.y;
    __shared__ __align__(16) float vs[5 * 1028];
    int tid = threadIdx.x;
    int lane = tid & 63, wid = tid >> 6;
    float acc[8][5];
#pragma unroll
    for (int r = 0; r < 8; r++)
#pragma unroll
        for (int w = 0; w < 5; w++) acc[r][w] = 0.f;

    for (int c = 0; c < 4; c++) {
        __syncthreads();
        for (int idx = tid; idx < 5120; idx += 256) {
            int w = idx >> 10, dd = idx & 1023;
            vs[w * 1028 + dd] = vbuf[(size_t)(b * NW + w) * DIM + c * 1024 + dd];
        }
        __syncthreads();
#pragma unroll
        for (int ri = 0; ri < 8; ri++) {
            int r = wid + ri * 4;
            if (r < 30) {
                int q = qt * 30 + r;
                const float* qp = query + (size_t)(b * NQ + q) * DIM + c * 1024;
#pragma unroll
                for (int j = 0; j < 4; j++) {
                    int d = lane * 4 + j * 256;
                    float4 qv = *(const float4*)(qp + d);
#pragma unroll
                    for (int w = 0; w < 5; w++) {
                        float4 vv = *(const float4*)(&vs[w * 1028 + d]);
                        acc[ri][w] += qv.x * vv.x + qv.y * vv.y + qv.z * vv.z + qv.w * vv.w;
                    }
                }
            }
        }
    }
#pragma unroll
    for (int ri = 0; ri < 8; ri++) {
        int r = wid + ri * 4;
#pragma unroll
        for (int w = 0; w < 5; w++) {
            float v = acc[ri][w];
            for (int off = 32; off > 0; off >>= 1) v += __shfl_xor(v, off, 64);
            if (r < 30 && lane == 0)
                out[(size_t)(b * NQ + qt * 30 + r) * NW + w] = v;
        }
    }
}

// ---------------------------------------------------------------------------
extern "C" void kernel_launch(void* const* d_in, const int* in_sizes, int n_in,
                              void* d_out, int out_size, void* d_ws, size_t ws_size,
                              hipStream_t stream) {
    const float* query   = (const float*)d_in[0];
    const float* support = (const float*)d_in[1];
    const int*   labels  = (const int*)d_in[2];
    float* out = (float*)d_out;
    float* ws  = (float*)d_ws;

    float* Kg   = ws + OFF_K;
    float* Kp   = ws + OFF_W;   // gram triangle partials (dead after reduce)
    float* vbuf = ws + OFF_W;   // alias (live after QP)
    float* z    = ws + OFF_Z;

    gram8<<<dim3(8, T_TASKS), 256, 0, stream>>>(support, Kp);
    gram_reduce<<<(T_TASKS * 5776 + 255) / 256, 256, 0, stream>>>(Kp, Kg);
    qp_solve<<<T_TASKS, 256, 0, stream>>>(Kg, labels, z);
    v_kernel<<<dim3(16, T_TASKS), 256, 0, stream>>>(support, z, vbuf);
    logits_kernel<<<dim3(5, T_TASKS), 256, 0, stream>>>(query, vbuf, out);
}